// Round 13
// baseline (324.084 us; speedup 1.0000x reference)
//
#include <hip/hip_runtime.h>
#include <hip/hip_bf16.h>

#define EPS 1e-5f

typedef short bf16x8 __attribute__((ext_vector_type(8)));
typedef float f32x4  __attribute__((ext_vector_type(4)));

__device__ __forceinline__ unsigned short f2bf(float f) {
    __hip_bfloat16 h = __float2bfloat16(f);
    return *(unsigned short*)&h;
}
__device__ __forceinline__ float bf2f(unsigned short u) {
    __hip_bfloat16 h = *(__hip_bfloat16*)&u;
    return __bfloat162float(h);
}

// ---------------------------------------------------------------------------
// packA: MFMA A-fragment packing (stages 2-3, generic tap-in-K)
// ---------------------------------------------------------------------------
__device__ __forceinline__ void packA(const float* __restrict__ w,
                                      unsigned short* __restrict__ Apk,
                                      int i, int CI, int COTALL)
{
    const int j = i & 7, lane = (i >> 3) & 63, pc = i >> 9;
    const int p = pc / COTALL, cot = pc % COTALL;
    const int kidx = p * 32 + (lane >> 4) * 8 + j;
    const int tap = kidx / CI, ci = kidx % CI;
    const int co = cot * 16 + (lane & 15);
    Apk[i] = f2bf((tap < 25) ? w[((size_t)co * CI + ci) * 25 + tap] : 0.f);
}

// ---------------------------------------------------------------------------
// FUSED conv1 + all weight prep. 1D grid:
//   blocks [0, NB_PREP): prep segments (scsh234 | A2 | A3 | A4pair | wfcT)
//   blocks [NB_PREP, +12480): conv1 tiles (self-contained weights)
// conv1: x [8,1,100,7500] -> c1o bf16 [120][50][250][16], TW=64.
// ---------------------------------------------------------------------------
#define NB_PREP 1205
__global__ __launch_bounds__(256) void conv1_prep(
    const float* __restrict__ x, const float* __restrict__ w1,
    const float* __restrict__ g1, const float* __restrict__ be1,
    const float* __restrict__ m1, const float* __restrict__ v1,
    const float* __restrict__ b1,
    const float* __restrict__ w2, const float* __restrict__ w3,
    const float* __restrict__ w4, const float* __restrict__ wfc,
    const float* __restrict__ g2, const float* __restrict__ be2,
    const float* __restrict__ m2, const float* __restrict__ v2,
    const float* __restrict__ b2,
    const float* __restrict__ g3, const float* __restrict__ be3,
    const float* __restrict__ m3, const float* __restrict__ v3,
    const float* __restrict__ b3,
    const float* __restrict__ g4, const float* __restrict__ be4,
    const float* __restrict__ m4, const float* __restrict__ v4,
    const float* __restrict__ b4,
    float* __restrict__ scsh, unsigned short* __restrict__ A2,
    unsigned short* __restrict__ A3, unsigned short* __restrict__ A4,
    unsigned short* __restrict__ wfcT, unsigned short* __restrict__ out)
{
    if (blockIdx.x < NB_PREP) {
        // ---- prep branch ----
        constexpr int S0 = 128, S1 = S0 + 13312, S2 = S1 + 51200;
        constexpr int S3 = S2 + 53248, S4 = S3 + 190464;
        const int idx = blockIdx.x * 256 + threadIdx.x;
        if (idx < S0) {
            const int t = idx;
            if (t < 32) {
                const float sc = g2[t] / sqrtf(v2[t] + EPS);
                scsh[t] = sc; scsh[32 + t] = (b2[t] - m2[t]) * sc + be2[t];
            } else if (t < 96) {
                const int c = t - 32;
                const float sc = g3[c] / sqrtf(v3[c] + EPS);
                scsh[64 + c] = sc; scsh[128 + c] = (b3[c] - m3[c]) * sc + be3[c];
            } else {
                const int c = t - 96;
                const float sc = g4[c] / sqrtf(v4[c] + EPS);
                scsh[192 + c] = sc; scsh[224 + c] = (b4[c] - m4[c]) * sc + be4[c];
            }
        } else if (idx < S1) {
            packA(w2, A2, idx - S0, 16, 2);
        } else if (idx < S2) {
            packA(w3, A3, idx - S1, 32, 4);
        } else if (idx < S3) {
            // A4 paired packing for fused stage4: pc = p*2+ct, p = qt*13+tp
            const int i = idx - S2;
            const int j = i & 7, lane = (i >> 3) & 63, pc = i >> 9;
            const int p = pc >> 1, ct = pc & 1;
            const int g = lane >> 4;
            const int tp = p % 13, qt = p / 13;
            const int tap = tp * 2 + (g >> 1);
            const int ci = qt * 16 + (g & 1) * 8 + j;
            const int co = ct * 16 + (lane & 15);
            A4[i] = f2bf((tap < 25) ? w4[((size_t)co * 64 + ci) * 25 + tap] : 0.f);
        } else if (idx < S4) {
            const int i = idx - S3;
            const int o = i / 5952, j = i % 5952;
            const int c = j & 31, yx = j >> 5;
            wfcT[i] = f2bf(wfc[(size_t)o * 5952 + c * 186 + yx]);
        }
        return;
    }

    // ---- conv1 branch ----
    constexpr int RSTR = 70;
    __shared__ unsigned short tile[12 * RSTR];
    const int t = blockIdx.x - NB_PREP;           // 0..12479
    const int xt = t & 7, yt = (t >> 3) % 13, n = t / 104;
    const int y0 = yt * 8, x0 = xt * 64;
    const int b = n / 15, c = n % 15;
    const float* xb = x + (size_t)b * 100 * 7500 + (size_t)c * 500;
    const int tid = threadIdx.x;

    for (int i = tid; i < 12 * 68; i += 256) {
        const int yy = i / 68, xx = i % 68;
        const int gy = y0 - 2 + yy, gx = x0 - 2 + xx;
        float v = 0.f;
        if (gy >= 0 && gy < 100 && gx >= 0 && gx < 500) v = xb[gy * 7500 + gx];
        tile[yy * RSTR + xx] = f2bf(v);
    }

    const int lane = tid & 63, wav = tid >> 6;
    const int g = lane >> 4, c15 = lane & 15;

    // self-contained A-fragment: a[j] = w1[co=lane&15][k=g*8+j] (0 for k>=25)
    bf16x8 a;
    #pragma unroll
    for (int j = 0; j < 8; ++j) {
        const int k = g * 8 + j;
        ((unsigned short*)&a)[j] =
            (short)f2bf((k < 25) ? w1[(lane & 15) * 25 + k] : 0.f);
    }

    int off[8];
    #pragma unroll
    for (int j = 0; j < 8; ++j) {
        int tap = g * 8 + j;
        if (tap > 24) tap = 24;
        off[j] = (tap / 5) * RSTR + (tap % 5);
    }
    __syncthreads();

    f32x4 acc[2][4] = {};
    #pragma unroll
    for (int r = 0; r < 2; ++r)
        #pragma unroll
        for (int cg = 0; cg < 4; ++cg) {
            const int base = (2 * wav + r) * RSTR + cg * 16 + c15;
            bf16x8 bfrag;
            #pragma unroll
            for (int j = 0; j < 8; ++j)
                ((unsigned short*)&bfrag)[j] = (short)tile[base + off[j]];
            acc[r][cg] = __builtin_amdgcn_mfma_f32_16x16x32_bf16(a, bfrag, acc[r][cg], 0, 0, 0);
        }

    // epilogue: BN (computed inline) + ReLU + 2x2 maxpool + bf16 store
    const int py = yt * 4 + wav;
    float scr4[4], shr4[4];
    #pragma unroll
    for (int reg = 0; reg < 4; ++reg) {
        const int ch = g * 4 + reg;
        const float sc_ = g1[ch] / sqrtf(v1[ch] + EPS);
        scr4[reg] = sc_;
        shr4[reg] = (b1[ch] - m1[ch]) * sc_ + be1[ch];
    }
    #pragma unroll
    for (int cg = 0; cg < 4; ++cg) {
        const int px = (x0 >> 1) + cg * 8 + (c15 >> 1);
        ushort4 st;
        #pragma unroll
        for (int reg = 0; reg < 4; ++reg) {
            const float v0 = fmaxf(acc[0][cg][reg] * scr4[reg] + shr4[reg], 0.f);
            const float v1_ = fmaxf(acc[1][cg][reg] * scr4[reg] + shr4[reg], 0.f);
            float mx = fmaxf(v0, v1_);
            mx = fmaxf(mx, __shfl_xor(mx, 1));
            (&st.x)[reg] = f2bf(mx);
        }
        if ((lane & 1) == 0 && py < 50 && px < 250)
            *(ushort4*)(out + (((size_t)n * 50 + py) * 250 + px) * 16 + g * 4) = st;
    }
}

// ---------------------------------------------------------------------------
// MFMA conv stages 2-3: channel-plane LDS, templated tile width TWP.
// ---------------------------------------------------------------------------
template <int CI, int CO, int H, int W, int PH, int PW, int NP, int NCT, int TWP>
__global__ __launch_bounds__(256) void mfma_conv(
    const unsigned short* __restrict__ in,
    const unsigned short* __restrict__ Apk,
    const float* __restrict__ sc, const float* __restrict__ sh,
    unsigned short* __restrict__ outp)
{
    constexpr int TH = 8, COLS = TWP + 4, ROWS = TH + 4, NCG = TWP / 16;
    constexpr int CPC = CI / 8;
    constexpr int PLANESZ = ROWS * COLS * 16;
    constexpr int PPAD = (CPC == 2) ? 64 : (CPC == 4 ? 32 : 16);
    constexpr int PSTR = PLANESZ + PPAD;
    constexpr int COTALL = CO / 16;
    constexpr int COB = CO / (16 * NCT);
    __shared__ char smem[CPC * PSTR];

    const int n = blockIdx.z / COB, cob = blockIdx.z % COB;
    const int ytile = blockIdx.y * TH, xtile = blockIdx.x * TWP;
    const int tid = threadIdx.x;

    for (int i = tid; i < ROWS * COLS * CPC; i += 256) {
        const int cell = i / CPC, ch = i % CPC;
        const int yy = cell / COLS, xx = cell % COLS;
        const int gy = ytile - 2 + yy, gx = xtile - 2 + xx;
        uint4 val = make_uint4(0, 0, 0, 0);
        if (gy >= 0 && gy < H && gx >= 0 && gx < W)
            val = *(const uint4*)(in + ((((size_t)n * H + gy) * W + gx) * CI + ch * 8));
        *(uint4*)(smem + ch * PSTR + cell * 16) = val;
    }
    __syncthreads();

    const int lane = tid & 63, wav = tid >> 6;
    const int g = lane >> 4, c15 = lane & 15;
    const bool hi = (lane >= 32);
    const int plane = (CI == 16) ? (g & 1) : g;
    const char* bbase = smem + plane * PSTR + ((wav * 2) * COLS + c15) * 16;

    f32x4 acc[2][NCT][NCG] = {};

    #pragma unroll
    for (int p = 0; p < NP; ++p) {
        int Dv = 0;
        if (CI == 16) {
            int t0 = p * 2;     if (t0 > 24) t0 = 24;
            int t1 = p * 2 + 1; if (t1 > 24) t1 = 24;
            const int D0 = ((t0 / 5) * COLS + t0 % 5) * 16;
            const int D1 = ((t1 / 5) * COLS + t1 % 5) * 16;
            Dv = hi ? D1 : D0;
        }
        const int tap = (CI == 32) ? p : ((CI == 64) ? (p >> 1) : 0);
        const int pimm = (CI == 64) ? (p & 1) * 4 * PSTR : 0;

        bf16x8 a[NCT], b[2][NCG];
        #pragma unroll
        for (int ct = 0; ct < NCT; ++ct)
            a[ct] = *(const bf16x8*)(Apk +
                ((size_t)(p * COTALL + cob * NCT + ct) * 64 + lane) * 8);
        #pragma unroll
        for (int r = 0; r < 2; ++r)
            #pragma unroll
            for (int cg = 0; cg < NCG; ++cg) {
                const int imm = (CI == 16)
                    ? (r * COLS + cg * 16) * 16
                    : (((r + tap / 5) * COLS + cg * 16 + tap % 5) * 16 + pimm);
                b[r][cg] = *(const bf16x8*)(bbase + Dv + imm);
            }
        #pragma unroll
        for (int r = 0; r < 2; ++r)
            #pragma unroll
            for (int ct = 0; ct < NCT; ++ct)
                #pragma unroll
                for (int cg = 0; cg < NCG; ++cg)
                    acc[r][ct][cg] = __builtin_amdgcn_mfma_f32_16x16x32_bf16(
                        a[ct], b[r][cg], acc[r][ct][cg], 0, 0, 0);
    }

    const int py = blockIdx.y * 4 + wav;
    #pragma unroll
    for (int ct = 0; ct < NCT; ++ct) {
        const int coW = (cob * NCT + ct) * 16;
        const float4 scv = *(const float4*)(sc + coW + g * 4);
        const float4 shv = *(const float4*)(sh + coW + g * 4);
        #pragma unroll
        for (int cg = 0; cg < NCG; ++cg) {
            const int px = (xtile >> 1) + cg * 8 + (c15 >> 1);
            ushort4 st;
            #pragma unroll
            for (int reg = 0; reg < 4; ++reg) {
                const float scr = (&scv.x)[reg], shr = (&shv.x)[reg];
                const float v0 = fmaxf(acc[0][ct][cg][reg] * scr + shr, 0.f);
                const float v1 = fmaxf(acc[1][ct][cg][reg] * scr + shr, 0.f);
                float mx = fmaxf(v0, v1);
                mx = fmaxf(mx, __shfl_xor(mx, 1));
                (&st.x)[reg] = f2bf(mx);
            }
            if ((lane & 1) == 0 && py < PH && px < PW)
                *(ushort4*)(outp + (((size_t)n * PH + py) * PW + px) * CO + coW + g * 4) = st;
        }
    }
}

// ---------------------------------------------------------------------------
// Fused stage4 + FC: one block per n (384 thr = 6 waves, all active).
// Wave w owns pooled row py = w. feats -> LDS -> FC -> res[n][32].
// ---------------------------------------------------------------------------
__global__ __launch_bounds__(384) void conv4fc_kernel(
    const unsigned short* __restrict__ in,
    const unsigned short* __restrict__ Apk,
    const float* __restrict__ sc, const float* __restrict__ sh,
    const unsigned short* __restrict__ wfcT,
    const float* __restrict__ bfc, float* __restrict__ res)
{
    constexpr int COLS = 66, ROWS = 16;
    constexpr int PLANESZ = ROWS * COLS * 16;      // 16896
    constexpr int PSTR = PLANESZ + 32;             // 16928
    __shared__ char smem[2 * PSTR + 6 * 31 * 32 * 2];   // 45760 B
    unsigned short* feats = (unsigned short*)(smem + 2 * PSTR);

    const int n = blockIdx.x;
    const int tid = threadIdx.x;
    const int lane = tid & 63, wav = tid >> 6;     // wav 0..5
    const int g = lane >> 4, c15 = lane & 15;
    const bool hi = (lane >= 32);

    const char* bbase = smem + (g & 1) * PSTR + ((wav * 2) * COLS + c15) * 16;
    f32x4 acc[2][2][4] = {};                       // [r][ct][cg]

    for (int qt = 0; qt < 4; ++qt) {
        __syncthreads();                           // protect prior-quarter reads
        for (int i = tid; i < ROWS * COLS * 2; i += 384) {
            const int pl = i & 1, cell = i >> 1;
            const int row = cell / COLS, col = cell - row * COLS;
            const int gy = row - 2, gx = col - 2;
            uint4 val = make_uint4(0, 0, 0, 0);
            if (gy >= 0 && gy < 12 && gx >= 0 && gx < 62)
                val = *(const uint4*)(in +
                    ((((size_t)n * 12 + gy) * 62 + gx) * 64 + qt * 16 + pl * 8));
            *(uint4*)(smem + pl * PSTR + cell * 16) = val;
        }
        __syncthreads();
        #pragma unroll
        for (int tp = 0; tp < 13; ++tp) {
            const int p = qt * 13 + tp;
            int t0 = tp * 2;     if (t0 > 24) t0 = 24;
            int t1 = tp * 2 + 1; if (t1 > 24) t1 = 24;
            const int D0 = ((t0 / 5) * COLS + t0 % 5) * 16;
            const int D1 = ((t1 / 5) * COLS + t1 % 5) * 16;
            const int Dv = hi ? D1 : D0;
            bf16x8 a[2], b[2][4];
            #pragma unroll
            for (int ct = 0; ct < 2; ++ct)
                a[ct] = *(const bf16x8*)(Apk + ((size_t)(p * 2 + ct) * 64 + lane) * 8);
            #pragma unroll
            for (int r = 0; r < 2; ++r)
                #pragma unroll
                for (int cg = 0; cg < 4; ++cg)
                    b[r][cg] = *(const bf16x8*)(bbase + Dv + (r * COLS + cg * 16) * 16);
            #pragma unroll
            for (int r = 0; r < 2; ++r)
                #pragma unroll
                for (int ct = 0; ct < 2; ++ct)
                    #pragma unroll
                    for (int cg = 0; cg < 4; ++cg)
                        acc[r][ct][cg] = __builtin_amdgcn_mfma_f32_16x16x32_bf16(
                            a[ct], b[r][cg], acc[r][ct][cg], 0, 0, 0);
        }
    }

    // epilogue: BN + ReLU + pool2x2 -> feats LDS [6][31][32]
    {
        const int py = wav;
        #pragma unroll
        for (int ct = 0; ct < 2; ++ct) {
            const int coW = ct * 16;
            const float4 scv = *(const float4*)(sc + coW + g * 4);
            const float4 shv = *(const float4*)(sh + coW + g * 4);
            #pragma unroll
            for (int cg = 0; cg < 4; ++cg) {
                const int px = cg * 8 + (c15 >> 1);
                ushort4 st;
                #pragma unroll
                for (int reg = 0; reg < 4; ++reg) {
                    const float scr = (&scv.x)[reg], shr = (&shv.x)[reg];
                    const float v0 = fmaxf(acc[0][ct][cg][reg] * scr + shr, 0.f);
                    const float v1 = fmaxf(acc[1][ct][cg][reg] * scr + shr, 0.f);
                    float mx = fmaxf(v0, v1);
                    mx = fmaxf(mx, __shfl_xor(mx, 1));
                    (&st.x)[reg] = f2bf(mx);
                }
                if ((lane & 1) == 0 && px < 31)
                    *(ushort4*)(feats + (py * 31 + px) * 32 + coW + g * 4) = st;
            }
        }
    }
    __syncthreads();

    // FC: 6 waves x up-to-6 outputs; feats LDS . wfcT global
    #pragma unroll
    for (int oi = 0; oi < 6; ++oi) {
        const int o = wav + 6 * oi;
        if (o < 32) {
            const unsigned short* wr = wfcT + (size_t)o * 5952;
            float s = 0.f;
            #pragma unroll
            for (int ii = 0; ii < 12; ++ii) {
                const int j8 = (ii * 64 + lane) * 8;
                if (j8 < 5952) {
                    const bf16x8 fv = *(const bf16x8*)(feats + j8);
                    const bf16x8 wv = *(const bf16x8*)(wr + j8);
                    #pragma unroll
                    for (int q = 0; q < 8; ++q)
                        s += bf2f(((const unsigned short*)&fv)[q]) *
                             bf2f(((const unsigned short*)&wv)[q]);
                }
            }
            #pragma unroll
            for (int off = 32; off > 0; off >>= 1) s += __shfl_down(s, off, 64);
            if (lane == 0) res[n * 32 + o] = s + bfc[o];
        }
    }
}

// ---------------------------------------------------------------------------
// DPCNN head, one block of 512. res f32 [120,32] -> out [8,2]
// ---------------------------------------------------------------------------
__global__ __launch_bounds__(512) void dpcnn_kernel(
    const float* __restrict__ res,
    const float* __restrict__ wc3, const float* __restrict__ bc3,
    const float* __restrict__ wout, const float* __restrict__ bout,
    float* __restrict__ out)
{
    __shared__ float rr[8][15][32];
    __shared__ float ar[8][15][34];
    __shared__ float tr[8][15][34];
    __shared__ float px[8][15][16];
    __shared__ float wk[15][45];
    __shared__ float bk[15];

    const int tid = threadIdx.x;
    for (int i = tid; i < 15 * 45; i += 512) ((float*)wk)[i] = wc3[i];
    if (tid < 15) bk[tid] = bc3[tid];
    for (int i = tid; i < 8 * 15 * 32; i += 512) {
        const int h = i & 31, c = (i >> 5) % 15, b = i / 480;
        const float val = res[i];
        rr[b][c][h] = val;
        ar[b][c][h + 1] = fmaxf(val, 0.f);
    }
    for (int i = tid; i < 8 * 15; i += 512) {
        const int c = i % 15, b = i / 15;
        ar[b][c][0] = 0.f; ar[b][c][33] = 0.f;
        tr[b][c][0] = 0.f; tr[b][c][33] = 0.f;
    }
    __syncthreads();

    #define CONV45(SRC, BCH, CCH, HH)                                          \
        float s0 = bk[CCH], s1 = 0.f, s2 = 0.f;                                \
        {                                                                      \
            const float* srow = &SRC[BCH][0][HH];                              \
            const float* wrow = &wk[CCH][0];                                   \
            _Pragma("unroll")                                                  \
            for (int ci = 0; ci < 15; ++ci) {                                  \
                s0 += wrow[ci * 3 + 0] * srow[ci * 34 + 0];                    \
                s1 += wrow[ci * 3 + 1] * srow[ci * 34 + 1];                    \
                s2 += wrow[ci * 3 + 2] * srow[ci * 34 + 2];                    \
            }                                                                  \
        }                                                                      \
        const float val = s0 + s1 + s2;

    {
        for (int i = tid; i < 8 * 15 * 32; i += 512) {
            const int h = i & 31, cc = (i >> 5) % 15, b = i / 480;
            CONV45(ar, b, cc, h)
            tr[b][cc][h + 1] = fmaxf(val, 0.f);
        }
        __syncthreads();
        for (int i = tid; i < 8 * 15 * 32; i += 512) {
            const int h = i & 31, cc = (i >> 5) % 15, b = i / 480;
            CONV45(tr, b, cc, h)
            rr[b][cc][h] = val;
            ar[b][cc][h + 1] = fmaxf(val, 0.f);
        }
        __syncthreads();
    }

    for (int H = 32; H > 2; H >>= 1) {
        const int Hh = H >> 1;
        const int NE = 8 * 15 * Hh;
        for (int i = tid; i < NE; i += 512) {
            const int h = i % Hh, cc = (i / Hh) % 15, b = i / (15 * Hh);
            const float m0 = rr[b][cc][2 * h], m1 = rr[b][cc][2 * h + 1];
            const float m2 = (2 * h + 2 < H) ? rr[b][cc][2 * h + 2] : 0.f;
            const float pv = fmaxf(fmaxf(m0, m1), m2);
            px[b][cc][h] = pv;
            ar[b][cc][h + 1] = fmaxf(pv, 0.f);
            if (h == 0) ar[b][cc][0] = 0.f;
            if (h == Hh - 1) ar[b][cc][Hh + 1] = 0.f;
        }
        __syncthreads();
        for (int i = tid; i < NE; i += 512) {
            const int h = i % Hh, cc = (i / Hh) % 15, b = i / (15 * Hh);
            CONV45(ar, b, cc, h)
            tr[b][cc][h + 1] = fmaxf(val, 0.f);
            if (h == 0) tr[b][cc][0] = 0.f;
            if (h == Hh - 1) tr[b][cc][Hh + 1] = 0.f;
        }
        __syncthreads();
        for (int i = tid; i < NE; i += 512) {
            const int h = i % Hh, cc = (i / Hh) % 15, b = i / (15 * Hh);
            CONV45(tr, b, cc, h)
            const float rv = val + px[b][cc][h];
            rr[b][cc][h] = rv;
            ar[b][cc][h + 1] = fmaxf(rv, 0.f);
        }
        __syncthreads();
    }
    #undef CONV45

    if (tid < 16) {
        const int b = tid >> 1, o = tid & 1;
        float s = bout[o];
        for (int c = 0; c < 15; ++c)
            #pragma unroll
            for (int h = 0; h < 2; ++h)
                s += wout[o * 30 + c * 2 + h] * rr[b][c][h];
        out[b * 2 + o] = s;
    }
}

// ---------------------------------------------------------------------------
extern "C" void kernel_launch(void* const* d_in, const int* in_sizes, int n_in,
                              void* d_out, int out_size, void* d_ws, size_t ws_size,
                              hipStream_t stream)
{
    const float* x = (const float*)d_in[0];
    const float* w1 = (const float*)d_in[1];  const float* b1 = (const float*)d_in[2];
    const float* g1 = (const float*)d_in[3];  const float* be1 = (const float*)d_in[4];
    const float* m1 = (const float*)d_in[5];  const float* v1 = (const float*)d_in[6];
    const float* w2 = (const float*)d_in[7];  const float* b2 = (const float*)d_in[8];
    const float* g2 = (const float*)d_in[9];  const float* be2 = (const float*)d_in[10];
    const float* m2 = (const float*)d_in[11]; const float* v2 = (const float*)d_in[12];
    const float* w3 = (const float*)d_in[13]; const float* b3 = (const float*)d_in[14];
    const float* g3 = (const float*)d_in[15]; const float* be3 = (const float*)d_in[16];
    const float* m3 = (const float*)d_in[17]; const float* v3 = (const float*)d_in[18];
    const float* w4 = (const float*)d_in[19]; const float* b4 = (const float*)d_in[20];
    const float* g4 = (const float*)d_in[21]; const float* be4 = (const float*)d_in[22];
    const float* m4 = (const float*)d_in[23]; const float* v4 = (const float*)d_in[24];
    const float* wfc = (const float*)d_in[25]; const float* bfc = (const float*)d_in[26];
    const float* wc3 = (const float*)d_in[27]; const float* bc3 = (const float*)d_in[28];
    const float* wout = (const float*)d_in[29]; const float* bout = (const float*)d_in[30];
    float* out = (float*)d_out;

    (void)in_sizes; (void)n_in; (void)out_size; (void)ws_size;

    // ---- workspace layout (float offsets) ----
    float* wsf = (float*)d_ws;
    float* res   = wsf;                               // [120*32]
    float* scsh  = wsf + 3840;                        // 256 floats
    float* sc2 = scsh, *sh2 = scsh + 32;
    float* sc3 = scsh + 64, *sh3 = scsh + 128;
    float* sc4 = scsh + 192, *sh4 = scsh + 224;
    unsigned short* A2  = (unsigned short*)(wsf + 4416);      // 13312 sh
    unsigned short* A3  = (unsigned short*)(wsf + 11072);     // 51200 sh
    unsigned short* A4  = (unsigned short*)(wsf + 36672);     // 53248 sh
    unsigned short* c1o = (unsigned short*)(wsf + 63360);     // [120][50][250][16]
    unsigned short* c2o = (unsigned short*)(wsf + 12063360);  // [120][25][125][32]
    unsigned short* c3o = (unsigned short*)(wsf + 18063360);  // [120][12][62][64]
    unsigned short* wfcT = (unsigned short*)(wsf + 20920320); // 190464 sh

    // ---- pipeline (5 launches) ----
    conv1_prep<<<NB_PREP + 12480, 256, 0, stream>>>(
        x, w1, g1, be1, m1, v1, b1,
        w2, w3, w4, wfc,
        g2, be2, m2, v2, b2, g3, be3, m3, v3, b3, g4, be4, m4, v4, b4,
        scsh, A2, A3, A4, wfcT, c1o);
    mfma_conv<16, 32, 50, 250, 25, 125, 13, 2, 64><<<dim3(4, 7, 120), 256, 0, stream>>>(
        c1o, A2, sc2, sh2, c2o);
    mfma_conv<32, 64, 25, 125, 12, 62, 25, 4, 32><<<dim3(4, 3, 120), 256, 0, stream>>>(
        c2o, A3, sc3, sh3, c3o);
    conv4fc_kernel<<<dim3(120), 384, 0, stream>>>(
        c3o, A4, sc4, sh4, wfcT, bfc, res);
    dpcnn_kernel<<<dim3(1), 512, 0, stream>>>(res, wc3, bc3, wout, bout, out);
}